// Round 3
// baseline (135724.719 us; speedup 1.0000x reference)
//
#include <hip/hip_runtime.h>
#include <stdint.h>

// BetterMCMC: bit-exact replication of the JAX reference MH chain (verified R2, absmax=0).
// R3 optimization: values are carried, not re-fetched.
//  - bigramT in d_ws: column gathers become row gathers (same f32 bits).
//  - s_pairw LDS cache of bigram[perm[j],perm[j+1]]: phase-3's 4095 scattered loads -> LDS rearrange + <=3 global loads.
//  - all 2559x4096 gumbels precomputed GPU-wide into d_ws (identical f64 log path).
// Decision path (threefry w1^w2, f64 exp/log, serial left-to-right fp32 sums) is unchanged bit-for-bit.

#define NW 4096
#define NSTEPS 2559
#define NTHREADS 1024
#define NWAVES 16
#define PER_T (NW / NTHREADS)   // 4

typedef unsigned long long u64;
typedef uint32_t u32;

__device__ __forceinline__ u32 rotl32(u32 v, u32 r) { return (v << r) | (v >> (32u - r)); }

// Threefry-2x32, 20 rounds, exactly as jax/_src/prng.py threefry2x32.
__device__ __forceinline__ void tf2x32(u32 k0, u32 k1, u32 x0, u32 x1, u32* o0, u32* o1) {
  u32 ks2 = k0 ^ k1 ^ 0x1BD11BDAu;
  x0 += k0; x1 += k1;
#define TFR(r0, r1, r2, r3)                      \
  x0 += x1; x1 = rotl32(x1, r0); x1 ^= x0;       \
  x0 += x1; x1 = rotl32(x1, r1); x1 ^= x0;       \
  x0 += x1; x1 = rotl32(x1, r2); x1 ^= x0;       \
  x0 += x1; x1 = rotl32(x1, r3); x1 ^= x0;
  TFR(13, 15, 26, 6)  x0 += k1;  x1 += ks2 + 1u;
  TFR(17, 29, 16, 24) x0 += ks2; x1 += k0 + 2u;
  TFR(13, 15, 26, 6)  x0 += k0;  x1 += k1 + 3u;
  TFR(17, 29, 16, 24) x0 += k1;  x1 += ks2 + 4u;
  TFR(13, 15, 26, 6)  x0 += ks2; x1 += k0 + 5u;
#undef TFR
  *o0 = x0; *o1 = x1;
}

__device__ __forceinline__ float unif01(u32 bits) {
  return __uint_as_float((bits >> 9) | 0x3f800000u) - 1.0f;
}

__device__ __forceinline__ u32 fkey(float f) {
  u32 b = __float_as_uint(f);
  return b ^ ((b >> 31) ? 0xFFFFFFFFu : 0x80000000u);
}

// ---------------- prep kernels (massively parallel, run per call) ----------------

#define TT 32
__global__ void transpose_k(const float* __restrict__ in, float* __restrict__ out) {
  __shared__ float tile[TT][TT + 1];
  int x = blockIdx.x * TT + threadIdx.x;
  int y = blockIdx.y * TT + threadIdx.y;
  for (int j = 0; j < TT; j += 8) tile[threadIdx.y + j][threadIdx.x] = in[(u64)(y + j) * NW + x];
  __syncthreads();
  x = blockIdx.y * TT + threadIdx.x;
  y = blockIdx.x * TT + threadIdx.y;
  for (int j = 0; j < TT; j += 8) out[(u64)(y + j) * NW + x] = tile[threadIdx.x][threadIdx.y + j];
}

__global__ void gumbel_k(float* __restrict__ gumb) {
  long long idx = (long long)blockIdx.x * blockDim.x + threadIdx.x;
  if (idx >= (long long)NSTEPS * NW) return;
  int t = (int)(idx >> 12);
  int i = (int)(idx & (NW - 1));
  u32 kt0, kt1, kc0, kc1, ba, bb;
  tf2x32(0u, 42u, 0u, (u32)t, &kt0, &kt1);        // keys[t]
  tf2x32(kt0, kt1, 0u, 1u, &kc0, &kc1);            // k_cat = split(keys[t],3)[1]
  tf2x32(kc0, kc1, 0u, (u32)i, &ba, &bb);
  float u = unif01(ba ^ bb);
  if (u == 0.0f) u = 1.17549435e-38f;
  float t1 = (float)log((double)u);
  float t2 = (float)log((double)(-t1));
  gumb[idx] = -t2;                                 // same bits as in-loop path
}

// ---------------- main chain kernel (fast path) ----------------

__global__ __launch_bounds__(NTHREADS)
void mcmc_fast(const float* __restrict__ bigram,
               const float* __restrict__ bigT,
               const float* __restrict__ gumb,
               const float* __restrict__ startv,
               const float* __restrict__ endv,
               int* __restrict__ out) {
  __shared__ unsigned short s_perm[NW];
  __shared__ float  s_logit[NW];
  __shared__ float  s_gath[NW];    // sample pair values (0..4094)
  __shared__ float  s_pairw[NW];   // current perm pair values (0..4094)
  __shared__ float  s_redf[NWAVES];
  __shared__ u64    s_redu[NWAVES];
  __shared__ double s_redd[NWAVES];
  __shared__ float  s_m, s_Z, s_w, s_u;
  __shared__ int    s_pos, s_tm, s_np, s_acc;

  const int tid = threadIdx.x;
  const int lane = tid & 63;
  const int wid = tid >> 6;

  // init: identity permutation; pairw/gath = bigram[j, j+1]; w0 via sequential fp32 sum
  for (int i = tid; i < NW; i += NTHREADS) s_perm[i] = (unsigned short)i;
  for (int j = tid; j < NW - 1; j += NTHREADS) {
    float v = bigram[(u64)j * NW + (j + 1)];
    s_gath[j] = v;
    s_pairw[j] = v;
  }
  __syncthreads();
  if (tid == 0) {
    float S = 0.0f;
    for (int j = 0; j < NW - 1; ++j) S += s_gath[j];
    S = S + startv[0];
    S = S + endv[NW - 1];
    s_w = S;
  }
  __syncthreads();

  for (int t = 0; t < NSTEPS; ++t) {
    // ---- phase 0: key derivation, removal position, accept-uniform (thread 0) ----
    if (tid == 0) {
      u32 kt0, kt1;
      tf2x32(0u, 42u, 0u, (u32)t, &kt0, &kt1);       // keys[t] = split(key(42), 2559)[t]
      u32 kp0, kp1, ku0, ku1;
      tf2x32(kt0, kt1, 0u, 0u, &kp0, &kp1);          // k_pos
      tf2x32(kt0, kt1, 0u, 2u, &ku0, &ku1);          // k_u
      u32 k2a, k2b, ra, rb;
      tf2x32(kp0, kp1, 0u, 1u, &k2a, &k2b);          // k2 = split(k_pos)[1]
      tf2x32(k2a, k2b, 0u, 0u, &ra, &rb);
      int pos = (int)((ra ^ rb) & (u32)(NW - 1));    // bits = w1 ^ w2
      s_pos = pos;
      s_tm = (int)s_perm[pos];
      u32 ua, ub;
      tf2x32(ku0, ku1, 0u, 0u, &ua, &ub);
      s_u = unif01(ua ^ ub);
    }
    __syncthreads();
    const int pos = s_pos, tm = s_tm;
    const u64 rowB = (u64)tm * NW;   // bigram row tm base
    const u64 rowT = (u64)tm * NW;   // bigT row tm base (column tm of bigram)

    // ---- phase 1: insertion logits + max ----
    float lmax = -3.402823466e+38f;
    for (int i = tid; i < NW; i += NTHREADS) {
      float li;
      if (i == 0) {
        int r = s_perm[(0 >= pos) ? 1 : 0];
        li = startv[tm] + bigram[rowB + r];
      } else if (i == NW - 1) {
        int l = s_perm[((NW - 2) >= pos) ? (NW - 1) : (NW - 2)];
        li = endv[tm] + bigT[rowT + l];
      } else {
        int l = s_perm[((i - 1) >= pos) ? i : (i - 1)];
        int r = s_perm[(i >= pos) ? (i + 1) : i];
        li = bigT[rowT + l] + bigram[rowB + r];      // fl(left + right), same bits as R2
      }
      s_logit[i] = li;
      lmax = fmaxf(lmax, li);
    }
    for (int o = 32; o > 0; o >>= 1) lmax = fmaxf(lmax, __shfl_down(lmax, o, 64));
    if (lane == 0) s_redf[wid] = lmax;
    __syncthreads();
    if (tid == 0) {
      float m = s_redf[0];
      for (int w = 1; w < NWAVES; ++w) m = fmaxf(m, s_redf[w]);
      s_m = m;
    }
    __syncthreads();
    const float m = s_m;

    // ---- phase 2: softmax denominator Z + gumbel argmax (gumbels precomputed) ----
    double zacc = 0.0;
    u64 best = 0;
    const u64 grow = (u64)t * NW;
    for (int i = tid; i < NW; i += NTHREADS) {
      float li = s_logit[i];
      float ex = (float)exp((double)(li - m));
      zacc += (double)ex;
      float g = gumb[grow + i];                      // coalesced
      float sv = g + li;
      u64 key = ((u64)fkey(sv) << 32) | (u32)(NW - 1 - i);
      if (key > best) best = key;
    }
    for (int o = 32; o > 0; o >>= 1) {
      u64 w = __shfl_down(best, o, 64);
      if (w > best) best = w;
      zacc += __shfl_down(zacc, o, 64);
    }
    if (lane == 0) { s_redu[wid] = best; s_redd[wid] = zacc; }
    __syncthreads();
    if (tid == 0) {
      u64 b = s_redu[0]; double z = s_redd[0];
      for (int w = 1; w < NWAVES; ++w) {
        if (s_redu[w] > b) b = s_redu[w];
        z += s_redd[w];
      }
      s_np = NW - 1 - (int)(b & 0xFFFFFFFFu);
      s_Z = (float)z;
    }
    __syncthreads();
    const int np = s_np;

    // ---- phase 3: assemble sample pair values from carried data ----
    // sample pair j: j<np-1 -> perm2pair(j); j==np-1 -> bigram[perm2[np-1],tm];
    //                j==np  -> bigram[tm,perm2[np]]; j>np -> perm2pair(j-1)
    // perm2pair(k):  k==pos-1 -> bigram[perm[pos-1],perm[pos+1]] (bridge, 1 load);
    //                k<pos-1 -> s_pairw[k]; k>=pos -> s_pairw[k+1]
    for (int j = tid; j < NW - 1; j += NTHREADS) {
      float v;
      if (j == np - 1) {
        int l = s_perm[(np - 1) + ((np - 1) >= pos)];     // perm2[np-1]
        v = bigT[rowT + l];                               // row hot from phase 1
      } else if (j == np) {
        int r = s_perm[np + (np >= pos)];                 // perm2[np]
        v = bigram[rowB + r];
      } else {
        int k = (j < np) ? j : (j - 1);
        if (k == pos - 1) {
          v = bigram[(u64)s_perm[pos - 1] * NW + s_perm[pos + 1]];   // bridge
        } else {
          v = (k < pos - 1) ? s_pairw[k] : s_pairw[k + 1];
        }
      }
      s_gath[j] = v;
    }
    __syncthreads();

    // ---- phase 4: sequential fp32 fresh sum + MH accept (thread 0) ----
    if (tid == 0) {
      int s0 = (0 < np) ? (int)s_perm[(0 >= pos) ? 1 : 0] : tm;
      int sl = ((NW - 1) == np) ? tm : (int)s_perm[(NW - 2) + ((NW - 2) >= pos)];
      float a0 = startv[s0];                              // issue early
      float a1 = endv[sl];
      float S = 0.0f;
#pragma unroll 8
      for (int j = 0; j < NW - 1; ++j) S += s_gath[j];    // left-to-right, init 0
      S = S + a0;
      S = S + a1;
      float dw = S - s_w;
      float e1 = (float)exp((double)dw);
      float en = (float)exp((double)(s_logit[np] - m));
      float eo = (float)exp((double)(s_logit[pos] - m));
      float pn = en / s_Z;
      float po = eo / s_Z;
      float acc = e1 * pn;
      acc = acc / po;
      acc = fminf(1.0f, acc);
      int accept = (acc > s_u) ? 1 : 0;
      s_acc = accept;
      if (accept) s_w = S;
    }
    __syncthreads();

    // ---- phase 5: apply insertion to s_perm + promote s_gath -> s_pairw if accepted ----
    unsigned short stash[PER_T];
    if (s_acc) {
      for (int k = 0; k < PER_T; ++k) {
        int i = tid + k * NTHREADS;
        stash[k] = (i < np) ? s_perm[i + (i >= pos)]
                            : ((i == np) ? (unsigned short)tm
                                         : s_perm[(i - 1) + ((i - 1) >= pos)]);
      }
    }
    __syncthreads();
    if (s_acc) {
      for (int k = 0; k < PER_T; ++k) {
        int i = tid + k * NTHREADS;
        s_perm[i] = stash[k];
      }
      for (int j = tid; j < NW - 1; j += NTHREADS) s_pairw[j] = s_gath[j];
    }
    __syncthreads();

    // ---- phase 6: emit thinned sample ----
    if (((t + 1) % 10) == 9) {
      int row = (t - 8) / 10;
      for (int i = tid; i < NW; i += NTHREADS) out[(u64)row * NW + i] = (int)s_perm[i];
    }
    __syncthreads();
  }
}

// ---------------- fallback (R2 kernel, verified) ----------------

__global__ __launch_bounds__(NTHREADS)
void mcmc_kernel(const float* __restrict__ bigram,
                 const float* __restrict__ startv,
                 const float* __restrict__ endv,
                 int* __restrict__ out) {
  __shared__ int    s_perm[NW];
  __shared__ float  s_logit[NW];
  __shared__ float  s_gath[NW];
  __shared__ float  s_redf[NWAVES];
  __shared__ u64    s_redu[NWAVES];
  __shared__ double s_redd[NWAVES];
  __shared__ float  s_m, s_Z, s_w;
  __shared__ int    s_pos, s_tm, s_np, s_acc;
  __shared__ u32    s_kcat0, s_kcat1, s_ku0, s_ku1;

  const int tid = threadIdx.x;
  const int lane = tid & 63;
  const int wid = tid >> 6;

  for (int i = tid; i < NW; i += NTHREADS) s_perm[i] = i;
  for (int j = tid; j < NW - 1; j += NTHREADS) s_gath[j] = bigram[(u64)j * NW + (j + 1)];
  __syncthreads();
  if (tid == 0) {
    float S = 0.0f;
    for (int j = 0; j < NW - 1; ++j) S += s_gath[j];
    S = S + startv[0];
    S = S + endv[NW - 1];
    s_w = S;
  }
  __syncthreads();

  for (int t = 0; t < NSTEPS; ++t) {
    if (tid == 0) {
      u32 kt0, kt1;
      tf2x32(0u, 42u, 0u, (u32)t, &kt0, &kt1);
      u32 kp0, kp1, kc0, kc1, ku0, ku1;
      tf2x32(kt0, kt1, 0u, 0u, &kp0, &kp1);
      tf2x32(kt0, kt1, 0u, 1u, &kc0, &kc1);
      tf2x32(kt0, kt1, 0u, 2u, &ku0, &ku1);
      u32 k2a, k2b, ra, rb;
      tf2x32(kp0, kp1, 0u, 1u, &k2a, &k2b);
      tf2x32(k2a, k2b, 0u, 0u, &ra, &rb);
      int pos = (int)((ra ^ rb) & (u32)(NW - 1));
      s_pos = pos;
      s_tm = s_perm[pos];
      s_kcat0 = kc0; s_kcat1 = kc1; s_ku0 = ku0; s_ku1 = ku1;
    }
    __syncthreads();
    const int pos = s_pos, tm = s_tm;

    float lmax = -3.402823466e+38f;
    for (int i = tid; i < NW; i += NTHREADS) {
      float li;
      if (i == 0) {
        int r = s_perm[(0 >= pos) ? 1 : 0];
        li = startv[tm] + bigram[(u64)tm * NW + r];
      } else if (i == NW - 1) {
        int l = s_perm[((NW - 2) >= pos) ? (NW - 1) : (NW - 2)];
        li = endv[tm] + bigram[(u64)l * NW + tm];
      } else {
        int l = s_perm[((i - 1) >= pos) ? i : (i - 1)];
        int r = s_perm[(i >= pos) ? (i + 1) : i];
        li = bigram[(u64)l * NW + tm] + bigram[(u64)tm * NW + r];
      }
      s_logit[i] = li;
      lmax = fmaxf(lmax, li);
    }
    for (int o = 32; o > 0; o >>= 1) lmax = fmaxf(lmax, __shfl_down(lmax, o, 64));
    if (lane == 0) s_redf[wid] = lmax;
    __syncthreads();
    if (tid == 0) {
      float m = s_redf[0];
      for (int w = 1; w < NWAVES; ++w) m = fmaxf(m, s_redf[w]);
      s_m = m;
    }
    __syncthreads();
    const float m = s_m;

    double zacc = 0.0;
    u64 best = 0;
    const u32 kc0 = s_kcat0, kc1 = s_kcat1;
    for (int i = tid; i < NW; i += NTHREADS) {
      float li = s_logit[i];
      float ex = (float)exp((double)(li - m));
      zacc += (double)ex;
      u32 ba, bb;
      tf2x32(kc0, kc1, 0u, (u32)i, &ba, &bb);
      float u = unif01(ba ^ bb);
      if (u == 0.0f) u = 1.17549435e-38f;
      float t1 = (float)log((double)u);
      float t2 = (float)log((double)(-t1));
      float g = -t2;
      float sv = g + li;
      u64 key = ((u64)fkey(sv) << 32) | (u32)(NW - 1 - i);
      if (key > best) best = key;
    }
    for (int o = 32; o > 0; o >>= 1) {
      u64 w = __shfl_down(best, o, 64);
      if (w > best) best = w;
      zacc += __shfl_down(zacc, o, 64);
    }
    if (lane == 0) { s_redu[wid] = best; s_redd[wid] = zacc; }
    __syncthreads();
    if (tid == 0) {
      u64 b = s_redu[0]; double z = s_redd[0];
      for (int w = 1; w < NWAVES; ++w) {
        if (s_redu[w] > b) b = s_redu[w];
        z += s_redd[w];
      }
      s_np = NW - 1 - (int)(b & 0xFFFFFFFFu);
      s_Z = (float)z;
    }
    __syncthreads();
    const int np = s_np;

    for (int j = tid; j < NW - 1; j += NTHREADS) {
      int a = (j < np) ? s_perm[j + (j >= pos)]
                       : ((j == np) ? tm : s_perm[(j - 1) + ((j - 1) >= pos)]);
      int j1 = j + 1;
      int b = (j1 < np) ? s_perm[j1 + (j1 >= pos)]
                        : ((j1 == np) ? tm : s_perm[(j1 - 1) + ((j1 - 1) >= pos)]);
      s_gath[j] = bigram[(u64)a * NW + b];
    }
    __syncthreads();

    if (tid == 0) {
      float S = 0.0f;
      for (int j = 0; j < NW - 1; ++j) S += s_gath[j];
      int s0 = (0 < np) ? s_perm[(0 >= pos) ? 1 : 0] : tm;
      int sl = ((NW - 1) == np) ? tm : s_perm[(NW - 2) + ((NW - 2) >= pos)];
      S = S + startv[s0];
      S = S + endv[sl];
      float dw = S - s_w;
      float e1 = (float)exp((double)dw);
      float en = (float)exp((double)(s_logit[np] - m));
      float eo = (float)exp((double)(s_logit[pos] - m));
      float pn = en / s_Z;
      float po = eo / s_Z;
      float acc = e1 * pn;
      acc = acc / po;
      acc = fminf(1.0f, acc);
      u32 ua, ub;
      tf2x32(s_ku0, s_ku1, 0u, 0u, &ua, &ub);
      float u = unif01(ua ^ ub);
      int accept = (acc > u) ? 1 : 0;
      s_acc = accept;
      if (accept) s_w = S;
    }
    __syncthreads();

    int stash[PER_T];
    if (s_acc) {
      for (int k = 0; k < PER_T; ++k) {
        int i = tid + k * NTHREADS;
        stash[k] = (i < np) ? s_perm[i + (i >= pos)]
                            : ((i == np) ? tm : s_perm[(i - 1) + ((i - 1) >= pos)]);
      }
    }
    __syncthreads();
    if (s_acc) {
      for (int k = 0; k < PER_T; ++k) {
        int i = tid + k * NTHREADS;
        s_perm[i] = stash[k];
      }
    }
    __syncthreads();

    if (((t + 1) % 10) == 9) {
      int row = (t - 8) / 10;
      for (int i = tid; i < NW; i += NTHREADS) out[(u64)row * NW + i] = s_perm[i];
    }
    __syncthreads();
  }
}

extern "C" void kernel_launch(void* const* d_in, const int* in_sizes, int n_in,
                              void* d_out, int out_size, void* d_ws, size_t ws_size,
                              hipStream_t stream) {
  const float* bigram = (const float*)d_in[1];
  const float* startv = (const float*)d_in[2];
  const float* endv   = (const float*)d_in[3];
  int* out = (int*)d_out;

  const size_t needT = (size_t)NW * NW * sizeof(float);        // 64 MB
  const size_t needG = (size_t)NSTEPS * NW * sizeof(float);    // ~41.9 MB

  if (ws_size >= needT + needG) {
    float* bigT = (float*)d_ws;
    float* gumb = (float*)((char*)d_ws + needT);
    hipLaunchKernelGGL(transpose_k, dim3(NW / TT, NW / TT), dim3(TT, 8), 0, stream,
                       bigram, bigT);
    long long ng = (long long)NSTEPS * NW;
    hipLaunchKernelGGL(gumbel_k, dim3((unsigned)((ng + 255) / 256)), dim3(256), 0, stream,
                       gumb);
    hipLaunchKernelGGL(mcmc_fast, dim3(1), dim3(NTHREADS), 0, stream,
                       bigram, bigT, gumb, startv, endv, out);
  } else {
    hipLaunchKernelGGL(mcmc_kernel, dim3(1), dim3(NTHREADS), 0, stream,
                       bigram, startv, endv, out);
  }
}